// Round 1
// 130.670 us; speedup vs baseline: 1.0519x; 1.0519x over previous
//
#include <hip/hip_runtime.h>
#include <hip/hip_bf16.h>

typedef _Float16 f16;
typedef _Float16 h4 __attribute__((ext_vector_type(4)));
typedef float f32x4 __attribute__((ext_vector_type(4)));

#define B_   128
#define PP_  1024
#define LP_  128
#define H_   256
#define NP_  131072
#define NL_  16384

// Projected-table row layout in tbl (f16, 178 rows x 256):
//   PE rows 0..127   = Ee@Wd1
//   PA rows 128..159 = Ea@Wd1
//   PB rows 160..161 = Eb@Wd1 + bd1
//   PL rows 162..177 = El@Wd1 + bd1

// ---------------------------------------------------------------- K1: tbl + ysum zero
// grid 256 x 256. bid<178: one projected table row; all bids zero ysum.
// This is the ONLY thing gpool depends on, so keep it tiny.
__global__ void __launch_bounds__(256) tbl_k(
    const float* __restrict__ W1,
    const float* __restrict__ Ee, const float* __restrict__ Ea,
    const float* __restrict__ Eb, const float* __restrict__ El,
    const float* __restrict__ bd1,
    f16* __restrict__ tbl, float* __restrict__ ysum)
{
  __shared__ float src[256];
  const int bid = blockIdx.x, tid = threadIdx.x;
  ysum[bid * 256 + tid] = 0.f;
  if (bid >= 178) return;

  const float* s;
  float badd = 0.f;
  if (bid < 128)      s = Ee + bid * 256;
  else if (bid < 160) s = Ea + (bid - 128) * 256;
  else if (bid < 162) { s = Eb + (bid - 160) * 256; badd = bd1[tid]; }
  else                { s = El + (bid - 162) * 256; badd = bd1[tid]; }
  src[tid] = s[tid];
  __syncthreads();
  float a0 = 0.f, a1 = 0.f, a2 = 0.f, a3 = 0.f;
#pragma unroll 4
  for (int k = 0; k < 256; k += 4) {
    a0 += src[k]     * W1[(k)     * 256 + tid];
    a1 += src[k + 1] * W1[(k + 1) * 256 + tid];
    a2 += src[k + 2] * W1[(k + 2) * 256 + tid];
    a3 += src[k + 3] * W1[(k + 3) * 256 + tid];
  }
  tbl[bid * 256 + tid] = (f16)(((a0 + a1) + (a2 + a3)) + badd);
}

// ---------------------------------------------------------------- K2: everything independent, one fat grid
// grid 3073 x 256:
//   bid 0..511   : wc row r=bid — WcP/WcL[r][j] (collapsed Wd2@Wa1, scaled 1/PP or 1/LP)
//   bid 512      : cvec
//   bid 513..768 : contact half-block cb=bid-513: b=cb>>1, half=cb&1 — min-d2 over
//                  512 protein points for all 128 ligands -> gmin[cb*128+lig]
//   bid 769..3072: gpool group (batch,g) — gather+silu+batch colsum -> ysum atomics
__global__ void __launch_bounds__(256, 4) mid_k(
    const float* __restrict__ W2, const float* __restrict__ Wa1,
    const float* __restrict__ ba1, const float* __restrict__ bd2,
    const float* __restrict__ ppos, const float* __restrict__ lpos,
    const int* __restrict__ pel, const int* __restrict__ paa,
    const int* __restrict__ pbb, const int* __restrict__ ltyp,
    const f16* __restrict__ tbl,
    float* __restrict__ wc, float* __restrict__ cvec,
    float* __restrict__ gmin, float* __restrict__ ysum)
{
  __shared__ __align__(16) float sm[1536];  // union: wc src(256) | contact px/py/pz(3x512) | gpool red(768)
  const int bid = blockIdx.x, tid = threadIdx.x;

  if (bid < 512) {
    // ---- collapsed weight rows
    const int half = bid >> 8, rr = bid & 255;
    sm[tid] = W2[rr * 256 + tid];
    __syncthreads();
    const float* W = Wa1 + half * 65536 + tid;
    float a0 = 0.f, a1 = 0.f, a2 = 0.f, a3 = 0.f;
#pragma unroll 4
    for (int n = 0; n < 256; n += 4) {
      a0 += sm[n]     * W[(n)     * 256];
      a1 += sm[n + 1] * W[(n + 1) * 256];
      a2 += sm[n + 2] * W[(n + 2) * 256];
      a3 += sm[n + 3] * W[(n + 3) * 256];
    }
    const float scale = half ? (1.f / (float)LP_) : (1.f / (float)PP_);
    wc[half * 65536 + rr * 256 + tid] = ((a0 + a1) + (a2 + a3)) * scale;

  } else if (bid == 512) {
    // ---- cvec
    float a = ba1[tid];
#pragma unroll 8
    for (int n = 0; n < 256; ++n)
      a += bd2[n] * (Wa1[n * 256 + tid] + Wa1[(256 + n) * 256 + tid]);
    cvec[tid] = a;

  } else if (bid < 769) {
    // ---- contact: one (batch, protein-half) per block; 2 threads per ligand
    const int cb = bid - 513, b = cb >> 1, half = cb & 1;
    float* px = sm;
    float* py = sm + 512;
    float* pz = sm + 1024;
#pragma unroll
    for (int r = 0; r < 2; ++r) {
      const int i = r * 256 + tid;
      const float* p = ppos + ((size_t)b * PP_ + half * 512 + i) * 3;
      px[i] = p[0]; py[i] = p[1]; pz[i] = p[2];
    }
    __syncthreads();
    const int lig = tid >> 1, part = tid & 1;
    const float* lp = lpos + ((size_t)b * LP_ + lig) * 3;
    const float lx = lp[0], ly = lp[1], lz = lp[2];
    const float4* X4 = (const float4*)(px + part * 256);
    const float4* Y4 = (const float4*)(py + part * 256);
    const float4* Z4 = (const float4*)(pz + part * 256);
    float m = 3.4e38f;
#pragma unroll 4
    for (int i = 0; i < 64; ++i) {
      float4 X = X4[i], Y = Y4[i], Z = Z4[i];
      float dx, dy, dz, d2;
      dx = lx - X.x; dy = ly - Y.x; dz = lz - Z.x;
      d2 = dx * dx + dy * dy + dz * dz; m = fminf(m, d2);
      dx = lx - X.y; dy = ly - Y.y; dz = lz - Z.y;
      d2 = dx * dx + dy * dy + dz * dz; m = fminf(m, d2);
      dx = lx - X.z; dy = ly - Y.z; dz = lz - Z.z;
      d2 = dx * dx + dy * dy + dz * dz; m = fminf(m, d2);
      dx = lx - X.w; dy = ly - Y.w; dz = lz - Z.w;
      d2 = dx * dx + dy * dy + dz * dz; m = fminf(m, d2);
    }
    m = fminf(m, __shfl_xor(m, 1));
    if (!part) gmin[cb * 128 + lig] = m;   // min-d2 of this half (sqrt deferred to head)

  } else {
    // ---- gather + silu + batch colsum
    const int idx = bid - 769;
    const int batch = idx / 18, g = idx % 18;
    const int wave = tid >> 6, lane = tid & 63;
    const int c0 = lane * 4;
    f32x4 acc = (f32x4){0.f, 0.f, 0.f, 0.f};

    if (g < 16) {
      const int base = batch * PP_ + g * 64 + wave * 16;
#pragma unroll 4
      for (int r = 0; r < 16; ++r) {
        const int i = base + r;
        h4 va = *(const h4*)(tbl + pel[i] * 256 + c0);
        h4 vb = *(const h4*)(tbl + 32768 + paa[i] * 256 + c0);
        h4 vc = *(const h4*)(tbl + 40960 + pbb[i] * 256 + c0);
#pragma unroll
        for (int k = 0; k < 4; ++k) {
          float pre = (float)va[k] + (float)vb[k] + (float)vc[k];
          acc[k] += pre * __builtin_amdgcn_rcpf(1.f + __expf(-pre));
        }
      }
    } else {
      const int base = batch * LP_ + (g - 16) * 64 + wave * 16;
#pragma unroll 4
      for (int r = 0; r < 16; ++r) {
        const int i = base + r;
        h4 v = *(const h4*)(tbl + 41472 + ltyp[i] * 256 + c0);
#pragma unroll
        for (int k = 0; k < 4; ++k) {
          float pre = (float)v[k];
          acc[k] += pre * __builtin_amdgcn_rcpf(1.f + __expf(-pre));
        }
      }
    }

    f32x4* red = (f32x4*)sm;
    if (wave) red[(wave - 1) * 64 + lane] = acc;
    __syncthreads();
    if (wave == 0) {
      f32x4 a1 = red[lane], a2 = red[64 + lane], a3 = red[128 + lane];
      float* pool = ysum + (g < 16 ? 0 : 32768) + batch * 256 + c0;
#pragma unroll
      for (int k = 0; k < 4; ++k)
        atomicAdd(pool + k, ((acc[k] + a1[k]) + (a2[k] + a3[k])));
    }
  }
}

// ---------------------------------------------------------------- K3: slim head
// One 512-thread block per batch. Combine gmin halves -> contact scalars,
// collapsed matvec, silu, dot with Wa2.
__global__ void __launch_bounds__(512) head_k(
    const float* __restrict__ ysum, const float* __restrict__ wc,
    const float* __restrict__ cvec, const float* __restrict__ Wa1,
    const float* __restrict__ Wa2, const float* __restrict__ ba2,
    const float* __restrict__ gmin, float* __restrict__ out)
{
  __shared__ float ysc[512];
  __shared__ float part[512];
  __shared__ float lmin[128];
  __shared__ float cls[2];
  __shared__ float red[4];
  const int b = blockIdx.x, tid = threadIdx.x;

  ysc[tid] = (tid < 256) ? ysum[b * 256 + tid]
                         : ysum[32768 + b * 256 + (tid - 256)];
  if (tid < 128) {
    const float m = fminf(gmin[(b * 2) * 128 + tid], gmin[(b * 2 + 1) * 128 + tid]);
    lmin[tid] = sqrtf(m);
  }
  __syncthreads();

  if (tid < 64) {
    const float a0 = lmin[tid], a1 = lmin[tid + 64];
    float sm = a0 + a1, mn = fminf(a0, a1);
#pragma unroll
    for (int off = 32; off; off >>= 1) {
      sm += __shfl_down(sm, off);
      mn = fminf(mn, __shfl_down(mn, off));
    }
    if (tid == 0) { cls[0] = sm * (1.f / (float)LP_); cls[1] = mn; }
  }

  // matvec partials: group gg covers k-half, thread = output col
  {
    const int gg = tid >> 8, j = tid & 255;
    const float* W = wc + gg * 65536 + j;
    const float* ys = ysc + gg * 256;
    float a[8];
#pragma unroll
    for (int u = 0; u < 8; ++u) a[u] = 0.f;
#pragma unroll 2
    for (int k = 0; k < 256; k += 8) {
#pragma unroll
      for (int u = 0; u < 8; ++u)
        a[u] += ys[k + u] * W[(k + u) * 256];
    }
    part[tid] = ((a[0] + a[1]) + (a[2] + a[3])) + ((a[4] + a[5]) + (a[6] + a[7]));
  }
  __syncthreads();

  if (tid < 256) {
    float pre = part[tid] + part[256 + tid] + cvec[tid]
              + cls[0] * Wa1[512 * 256 + tid] + cls[1] * Wa1[513 * 256 + tid];
    float si = pre * __builtin_amdgcn_rcpf(1.f + __expf(-pre));
    float p = si * Wa2[tid];
#pragma unroll
    for (int off = 32; off; off >>= 1) p += __shfl_down(p, off);
    if ((tid & 63) == 0) red[tid >> 6] = p;
  }
  __syncthreads();
  if (tid == 0) out[b] = (red[0] + red[1]) + (red[2] + red[3]) + ba2[0];
}

// ---------------------------------------------------------------- launch
extern "C" void kernel_launch(void* const* d_in, const int* in_sizes, int n_in,
                              void* d_out, int out_size, void* d_ws, size_t ws_size,
                              hipStream_t stream)
{
  const float* protein_pos = (const float*)d_in[0];
  const float* ligand_pos  = (const float*)d_in[1];
  const int*   pel  = (const int*)d_in[2];
  const int*   paa  = (const int*)d_in[3];
  const int*   pbb  = (const int*)d_in[4];
  const int*   ltyp = (const int*)d_in[5];
  const float* Ee  = (const float*)d_in[8];
  const float* Ea  = (const float*)d_in[9];
  const float* Eb  = (const float*)d_in[10];
  const float* El  = (const float*)d_in[11];
  const float* Wd1 = (const float*)d_in[12];
  const float* bd1 = (const float*)d_in[13];
  const float* Wd2 = (const float*)d_in[14];
  const float* bd2 = (const float*)d_in[15];
  const float* Wa1 = (const float*)d_in[16];
  const float* ba1 = (const float*)d_in[17];
  const float* Wa2 = (const float*)d_in[18];
  const float* ba2 = (const float*)d_in[19];
  float* out = (float*)d_out;

  char* ws = (char*)d_ws;
  f16*   tbl  = (f16*)(ws);                  // 178*256 f16 = 91136 B
  float* ysum = (float*)(ws + 98304);        // 65536 f32 = 262144 B
  float* wc   = (float*)(ws + 360448);       // 131072 f32 = 524288 B
  float* cvec = (float*)(ws + 884736);       // 1024 B
  float* gmin = (float*)(ws + 885760);       // 256*128 f32 = 131072 B

  tbl_k<<<256, 256, 0, stream>>>(Wd1, Ee, Ea, Eb, El, bd1, tbl, ysum);
  mid_k<<<3073, 256, 0, stream>>>(Wd2, Wa1, ba1, bd2, protein_pos, ligand_pos,
                                  pel, paa, pbb, ltyp, tbl, wc, cvec, gmin, ysum);
  head_k<<<B_, 512, 0, stream>>>(ysum, wc, cvec, Wa1, Wa2, ba2, gmin, out);
}